// Round 3
// baseline (1016.132 us; speedup 1.0000x reference)
//
#include <hip/hip_runtime.h>
#include <stdint.h>

#define WN 4096               // nodes
#define BN 32                 // batch
#define LN 96                 // gate layers
#define CN 16                 // owned nodes per block
#define HN 16                 // halo width (nodes)
#define NS (CN + HN)          // 32 node slots per block
#define NBLK (WN / CN)        // 256 blocks (1 per CU)
#define TPB (NS * BN)         // 1024 threads
#define NSS (LN / HN)         // 6 superstages of 16 gate layers

#define POISON64 0xAAAAAAAAAAAAAAAAULL

// main ring: 5 exchanges x NBLK x CN nodes x BN batch x 4 u64 (8 floats)
#define RING_SS_STRIDE ((size_t)NBLK * CN * BN * 4)
#define RING2_OFF ((size_t)(NSS - 1) * RING_SS_STRIDE)   // 2,621,440 u64 = 21 MB

static __device__ __forceinline__ float sigmoid_f(float z) {
    // 1 / (1 + 2^(-z*log2(e)))
    float e = __builtin_amdgcn_exp2f(z * -1.4426950408889634f);
    return __builtin_amdgcn_rcpf(1.0f + e);
}

static __device__ __forceinline__ uint64_t pack2(float a, float b) {
    union { float f[2]; uint64_t u; } u;
    u.f[0] = a; u.f[1] = b;
    return u.u;
}

static __device__ __forceinline__ void unpack2(uint64_t q, float& a, float& b) {
    union { uint64_t u; float f[2]; } u;
    u.u = q; a = u.f[0]; b = u.f[1];
}

// Sigmoid outputs are in (0,1): never bit-equal to the 0xAA poison or 0,
// so each u64 is its own ready-flag (verified correct in round 2).
static __device__ __forceinline__ uint64_t poll64(const uint64_t* p) {
    uint64_t q;
    do {
        q = __hip_atomic_load(p, __ATOMIC_RELAXED, __HIP_MEMORY_SCOPE_AGENT);
    } while (q == POISON64 || q == 0ULL);
    return q;
}

__global__ __launch_bounds__(TPB, 4) void rh_halo_kernel(
    const float* __restrict__ x,
    const float* __restrict__ w_top,
    const float* __restrict__ b_top,
    const float* __restrict__ w_gate,
    const float* __restrict__ b_gate,
    const float* __restrict__ w_prior,
    const float* __restrict__ b_prior,
    float* __restrict__ out,
    uint64_t* __restrict__ ring)
{
    const int tid  = threadIdx.x;
    const int j    = tid >> 5;               // node slot [0, NS)
    const int b    = tid & 31;               // batch lane
    const int blk  = blockIdx.x;
    const int node = (blk * CN - HN + j + WN) & (WN - 1);  // global node (wraps)
    const bool isn0 = (node == 0);           // routing-swap node
    const int leftblk = (blk + NBLK - 1) & (NBLK - 1);

    __shared__ float4 lodds[2][NS][BN];      // odd outputs, parity double-buffer

    float y[8];                               // current layer sigmoid outputs

    // ---------------- top layer: all NS slots (depends only on x) ----------
    {
        float xv = x[(size_t)b * WN + node];
        const float4* wt = (const float4*)(w_top + (size_t)node * 32);
        const float4* bt = (const float4*)(b_top + (size_t)node * 8);
        float4 c0 = bt[0], c1 = bt[1];
        float bb[8] = {c0.x, c0.y, c0.z, c0.w, c1.x, c1.y, c1.z, c1.w};
        #pragma unroll
        for (int o = 0; o < 8; ++o) {
            float4 a = wt[o];
            y[o] = sigmoid_f(xv * (a.x + a.y + a.z + a.w) + bb[o]);
        }
    }

    const float4* wg_base = (const float4*)w_gate;
    const float4* bg_base = (const float4*)b_gate;
    int par = 0;

    #pragma unroll 1
    for (int ss = 0; ss < NSS; ++ss) {
        // 16 local gate layers; valid window shrinks: slot j active iff j >= t
        #pragma unroll 1
        for (int t = 1; t <= HN; ++t) {
            const int g = ss * HN + t;       // gate layer 1..96 (w_gate idx g-1)

            // publish current odds (y valid for j >= t-1)
            if (j >= t - 1)
                lodds[par][j][b] = make_float4(y[1], y[3], y[5], y[7]);

            // prefetch this layer's weights before the barrier (hides latency)
            float4 wa[16], wb0, wb1;
            if (j >= t) {
                const float4* wrow = wg_base + ((size_t)(g - 1) * WN + node) * 16;
                const float4* brow = bg_base + ((size_t)(g - 1) * WN + node) * 2;
                #pragma unroll
                for (int i = 0; i < 16; ++i) wa[i] = wrow[i];
                wb0 = brow[0];
                wb1 = brow[1];
            }

            __syncthreads();

            if (j >= t) {
                float4 od = lodds[par][j - 1][b];
                // routing: evens = own y, odds = left-neighbor odds (node 0 swapped)
                float h0, h1, h2, h3, h4, h5, h6, h7;
                if (isn0) {
                    h0 = od.x; h2 = od.y; h4 = od.z; h6 = od.w;
                    h1 = y[0]; h3 = y[2]; h5 = y[4]; h7 = y[6];
                } else {
                    h0 = y[0]; h2 = y[2]; h4 = y[4]; h6 = y[6];
                    h1 = od.x; h3 = od.y; h5 = od.z; h7 = od.w;
                }
                float bb[8] = {wb0.x, wb0.y, wb0.z, wb0.w,
                               wb1.x, wb1.y, wb1.z, wb1.w};
                #pragma unroll
                for (int o = 0; o < 8; ++o) {
                    float4 a0 = wa[2 * o], a1 = wa[2 * o + 1];
                    float z = bb[o];
                    z += a0.x * h0 + a0.y * h1 + a0.z * h2 + a0.w * h3;
                    z += a1.x * h4 + a1.y * h5 + a1.z * h6 + a1.w * h7;
                    y[o] = sigmoid_f(z);
                }
            }
            par ^= 1;
        }

        // -------- superstage exchange (5 of them): owned y -> right neighbor
        if (ss < NSS - 1) {
            if (j >= HN) {
                uint64_t* slot = ring + (size_t)ss * RING_SS_STRIDE
                               + (((size_t)blk * CN + (j - HN)) * BN + b) * 4;
                __hip_atomic_store(slot + 0, pack2(y[0], y[1]),
                                   __ATOMIC_RELAXED, __HIP_MEMORY_SCOPE_AGENT);
                __hip_atomic_store(slot + 1, pack2(y[2], y[3]),
                                   __ATOMIC_RELAXED, __HIP_MEMORY_SCOPE_AGENT);
                __hip_atomic_store(slot + 2, pack2(y[4], y[5]),
                                   __ATOMIC_RELAXED, __HIP_MEMORY_SCOPE_AGENT);
                __hip_atomic_store(slot + 3, pack2(y[6], y[7]),
                                   __ATOMIC_RELAXED, __HIP_MEMORY_SCOPE_AGENT);
            } else {
                const uint64_t* src = ring + (size_t)ss * RING_SS_STRIDE
                                    + (((size_t)leftblk * CN + j) * BN + b) * 4;
                unpack2(poll64(src + 0), y[0], y[1]);
                unpack2(poll64(src + 1), y[2], y[3]);
                unpack2(poll64(src + 2), y[4], y[5]);
                unpack2(poll64(src + 3), y[6], y[7]);
            }
        }
    }

    // ---------------- final routing + prior (owned slots only) -------------
    // y = gate-96 output, valid for j in [HN, NS). Slot HN needs odds of the
    // left block's last owned node -> one tiny boundary exchange.
    if (j >= HN)
        lodds[par][j][b] = make_float4(y[1], y[3], y[5], y[7]);
    if (j == NS - 1) {
        uint64_t* slot = ring + RING2_OFF + ((size_t)blk * BN + b) * 2;
        __hip_atomic_store(slot + 0, pack2(y[1], y[3]),
                           __ATOMIC_RELAXED, __HIP_MEMORY_SCOPE_AGENT);
        __hip_atomic_store(slot + 1, pack2(y[5], y[7]),
                           __ATOMIC_RELAXED, __HIP_MEMORY_SCOPE_AGENT);
    }
    __syncthreads();

    if (j >= HN) {
        float od0, od1, od2, od3;
        if (j == HN) {
            const uint64_t* src = ring + RING2_OFF + ((size_t)leftblk * BN + b) * 2;
            unpack2(poll64(src + 0), od0, od1);
            unpack2(poll64(src + 1), od2, od3);
        } else {
            float4 t = lodds[par][j - 1][b];
            od0 = t.x; od1 = t.y; od2 = t.z; od3 = t.w;
        }
        float h0, h1, h2, h3, h4, h5, h6, h7;
        if (isn0) {
            h0 = od0;  h2 = od1;  h4 = od2;  h6 = od3;
            h1 = y[0]; h3 = y[2]; h5 = y[4]; h7 = y[6];
        } else {
            h0 = y[0]; h2 = y[2]; h4 = y[4]; h6 = y[6];
            h1 = od0;  h3 = od1;  h5 = od2;  h7 = od3;
        }
        const float4* wp = (const float4*)(w_prior + (size_t)node * 8);
        float4 p0 = wp[0], p1 = wp[1];
        float logit = b_prior[node]
            + p0.x * h0 + p0.y * h1 + p0.z * h2 + p0.w * h3
            + p1.x * h4 + p1.y * h5 + p1.z * h6 + p1.w * h7;
        out[(size_t)b * WN + node] = logit;
    }
}

extern "C" void kernel_launch(void* const* d_in, const int* in_sizes, int n_in,
                              void* d_out, int out_size, void* d_ws, size_t ws_size,
                              hipStream_t stream) {
    const float* x       = (const float*)d_in[0];
    const float* w_top   = (const float*)d_in[1];
    const float* b_top   = (const float*)d_in[2];
    const float* w_gate  = (const float*)d_in[3];
    const float* b_gate  = (const float*)d_in[4];
    const float* w_prior = (const float*)d_in[5];
    const float* b_prior = (const float*)d_in[6];
    float* out           = (float*)d_out;
    uint64_t* ring       = (uint64_t*)d_ws;  // 21.1 MB used (< 25.4 MB proven OK)

    hipLaunchKernelGGL(rh_halo_kernel, dim3(NBLK), dim3(TPB), 0, stream,
                       x, w_top, b_top, w_gate, b_gate, w_prior, b_prior,
                       out, ring);
}

// Round 5
// 383.385 us; speedup vs baseline: 2.6504x; 2.6504x over previous
//
#include <hip/hip_runtime.h>
#include <stdint.h>

#define WN 4096               // nodes
#define BN 32                 // batch
#define LN 96                 // gate layers
#define CN 16                 // owned nodes per block
#define HN 16                 // halo width (nodes)
#define NS (CN + HN)          // 32 node slots per block
#define NBLK (WN / CN)        // 256 blocks (1 per CU)
#define TPB (NS * BN)         // 1024 threads
#define NSS (LN / HN)         // 6 superstages of 16 gate layers

#define POISON64 0xAAAAAAAAAAAAAAAAULL

// main ring: 5 exchanges x NBLK x CN nodes x BN batch x 4 u64 (8 floats)
#define RING_SS_STRIDE ((size_t)NBLK * CN * BN * 4)
#define RING2_OFF ((size_t)(NSS - 1) * RING_SS_STRIDE)   // + 16 KB boundary ring

static __device__ __forceinline__ float sigmoid_f(float z) {
    // 1 / (1 + 2^(-z*log2(e)))
    float e = __builtin_amdgcn_exp2f(z * -1.4426950408889634f);
    return __builtin_amdgcn_rcpf(1.0f + e);
}

static __device__ __forceinline__ uint64_t pack2(float a, float b) {
    union { float f[2]; uint64_t u; } u;
    u.f[0] = a; u.f[1] = b;
    return u.u;
}

static __device__ __forceinline__ void unpack2(uint64_t q, float& a, float& b) {
    union { uint64_t u; float f[2]; } u;
    u.u = q; a = u.f[0]; b = u.f[1];
}

// Sigmoid outputs are in (0,1): never bit-equal to the 0xAA poison or 0,
// so each u64 is its own ready-flag (verified correct in rounds 2 and 3).
static __device__ __forceinline__ uint64_t poll64(const uint64_t* p) {
    uint64_t q;
    do {
        q = __hip_atomic_load(p, __ATOMIC_RELAXED, __HIP_MEMORY_SCOPE_AGENT);
    } while (q == POISON64 || q == 0ULL);
    return q;
}

__global__
__attribute__((amdgpu_flat_work_group_size(TPB, TPB), amdgpu_waves_per_eu(4, 4)))
void rh_halo_kernel(
    const float* __restrict__ x,
    const float* __restrict__ w_top,
    const float* __restrict__ b_top,
    const float* __restrict__ w_gate,
    const float* __restrict__ b_gate,
    const float* __restrict__ w_prior,
    const float* __restrict__ b_prior,
    float* __restrict__ out,
    uint64_t* __restrict__ ring)
{
    const int tid  = threadIdx.x;
    const int j    = tid >> 5;               // node slot [0, NS)
    const int b    = tid & 31;               // batch lane
    const int blk  = blockIdx.x;
    const int node = (blk * CN - HN + j + WN) & (WN - 1);  // global node (wraps)
    const bool isn0 = (node == 0);           // routing-swap node
    const int leftblk = (blk + NBLK - 1) & (NBLK - 1);

    __shared__ float4 lodds[2][NS][BN];      // odd outputs, parity double-buffer

    float y[8];                               // current layer sigmoid outputs

    // ---------------- top layer: all NS slots (depends only on x) ----------
    {
        float xv = x[(size_t)b * WN + node];
        const float4* wt = (const float4*)(w_top + (size_t)node * 32);
        const float4* bt = (const float4*)(b_top + (size_t)node * 8);
        float4 c0 = bt[0], c1 = bt[1];
        float bb[8] = {c0.x, c0.y, c0.z, c0.w, c1.x, c1.y, c1.z, c1.w};
        #pragma unroll
        for (int o = 0; o < 8; ++o) {
            float4 a = wt[o];
            y[o] = sigmoid_f(xv * (a.x + a.y + a.z + a.w) + bb[o]);
        }
    }

    const float4* wg_base = (const float4*)w_gate;
    const float4* bg_base = (const float4*)b_gate;
    int par = 0;

    #pragma unroll 1
    for (int ss = 0; ss < NSS; ++ss) {
        // 16 local gate layers; valid window shrinks: slot j active iff j >= t
        #pragma unroll 1
        for (int t = 1; t <= HN; ++t) {
            const int g = ss * HN + t;       // gate layer 1..96 (w_gate idx g-1)

            // publish current odds (y valid for j >= t-1)
            if (j >= t - 1)
                lodds[par][j][b] = make_float4(y[1], y[3], y[5], y[7]);

            __syncthreads();

            if (j >= t) {
                float4 od = lodds[par][j - 1][b];
                // routing: evens = own y, odds = left-neighbor odds (node 0 swapped)
                float h0, h1, h2, h3, h4, h5, h6, h7;
                if (isn0) {
                    h0 = od.x; h2 = od.y; h4 = od.z; h6 = od.w;
                    h1 = y[0]; h3 = y[2]; h5 = y[4]; h7 = y[6];
                } else {
                    h0 = y[0]; h2 = y[2]; h4 = y[4]; h6 = y[6];
                    h1 = od.x; h3 = od.y; h5 = od.z; h7 = od.w;
                }
                // stream this layer's weights straight into the MACs — no
                // register-resident prefetch (round-3 spill killer)
                const float4* wrow = wg_base + ((size_t)(g - 1) * WN + node) * 16;
                const float4* brow = bg_base + ((size_t)(g - 1) * WN + node) * 2;
                float4 c0 = brow[0], c1 = brow[1];
                float z[8] = {c0.x, c0.y, c0.z, c0.w, c1.x, c1.y, c1.z, c1.w};
                #pragma unroll
                for (int o = 0; o < 8; ++o) {
                    float4 a0 = wrow[2 * o], a1 = wrow[2 * o + 1];
                    z[o] += a0.x * h0 + a0.y * h1 + a0.z * h2 + a0.w * h3
                          + a1.x * h4 + a1.y * h5 + a1.z * h6 + a1.w * h7;
                }
                #pragma unroll
                for (int o = 0; o < 8; ++o) y[o] = sigmoid_f(z[o]);
            }
            par ^= 1;
        }

        // -------- superstage exchange (5 of them): owned y -> right neighbor
        if (ss < NSS - 1) {
            if (j >= HN) {
                uint64_t* slot = ring + (size_t)ss * RING_SS_STRIDE
                               + (((size_t)blk * CN + (j - HN)) * BN + b) * 4;
                __hip_atomic_store(slot + 0, pack2(y[0], y[1]),
                                   __ATOMIC_RELAXED, __HIP_MEMORY_SCOPE_AGENT);
                __hip_atomic_store(slot + 1, pack2(y[2], y[3]),
                                   __ATOMIC_RELAXED, __HIP_MEMORY_SCOPE_AGENT);
                __hip_atomic_store(slot + 2, pack2(y[4], y[5]),
                                   __ATOMIC_RELAXED, __HIP_MEMORY_SCOPE_AGENT);
                __hip_atomic_store(slot + 3, pack2(y[6], y[7]),
                                   __ATOMIC_RELAXED, __HIP_MEMORY_SCOPE_AGENT);
            } else {
                const uint64_t* src = ring + (size_t)ss * RING_SS_STRIDE
                                    + (((size_t)leftblk * CN + j) * BN + b) * 4;
                unpack2(poll64(src + 0), y[0], y[1]);
                unpack2(poll64(src + 1), y[2], y[3]);
                unpack2(poll64(src + 2), y[4], y[5]);
                unpack2(poll64(src + 3), y[6], y[7]);
            }
        }
    }

    // ---------------- final routing + prior (owned slots only) -------------
    // y = gate-96 output, valid for j in [HN, NS). Slot HN needs odds of the
    // left block's last owned node -> one tiny boundary exchange.
    if (j >= HN)
        lodds[par][j][b] = make_float4(y[1], y[3], y[5], y[7]);
    if (j == NS - 1) {
        uint64_t* slot = ring + RING2_OFF + ((size_t)blk * BN + b) * 2;
        __hip_atomic_store(slot + 0, pack2(y[1], y[3]),
                           __ATOMIC_RELAXED, __HIP_MEMORY_SCOPE_AGENT);
        __hip_atomic_store(slot + 1, pack2(y[5], y[7]),
                           __ATOMIC_RELAXED, __HIP_MEMORY_SCOPE_AGENT);
    }
    __syncthreads();

    if (j >= HN) {
        float od0, od1, od2, od3;
        if (j == HN) {
            const uint64_t* src = ring + RING2_OFF + ((size_t)leftblk * BN + b) * 2;
            unpack2(poll64(src + 0), od0, od1);
            unpack2(poll64(src + 1), od2, od3);
        } else {
            float4 t = lodds[par][j - 1][b];
            od0 = t.x; od1 = t.y; od2 = t.z; od3 = t.w;
        }
        float h0, h1, h2, h3, h4, h5, h6, h7;
        if (isn0) {
            h0 = od0;  h2 = od1;  h4 = od2;  h6 = od3;
            h1 = y[0]; h3 = y[2]; h5 = y[4]; h7 = y[6];
        } else {
            h0 = y[0]; h2 = y[2]; h4 = y[4]; h6 = y[6];
            h1 = od0;  h3 = od1;  h5 = od2;  h7 = od3;
        }
        const float4* wp = (const float4*)(w_prior + (size_t)node * 8);
        float4 p0 = wp[0], p1 = wp[1];
        float logit = b_prior[node]
            + p0.x * h0 + p0.y * h1 + p0.z * h2 + p0.w * h3
            + p1.x * h4 + p1.y * h5 + p1.z * h6 + p1.w * h7;
        out[(size_t)b * WN + node] = logit;
    }
}

extern "C" void kernel_launch(void* const* d_in, const int* in_sizes, int n_in,
                              void* d_out, int out_size, void* d_ws, size_t ws_size,
                              hipStream_t stream) {
    const float* x       = (const float*)d_in[0];
    const float* w_top   = (const float*)d_in[1];
    const float* b_top   = (const float*)d_in[2];
    const float* w_gate  = (const float*)d_in[3];
    const float* b_gate  = (const float*)d_in[4];
    const float* w_prior = (const float*)d_in[5];
    const float* b_prior = (const float*)d_in[6];
    float* out           = (float*)d_out;
    uint64_t* ring       = (uint64_t*)d_ws;  // 21.1 MB used (< 25.4 MB proven OK)

    hipLaunchKernelGGL(rh_halo_kernel, dim3(NBLK), dim3(TPB), 0, stream,
                       x, w_top, b_top, w_gate, b_gate, w_prior, b_prior,
                       out, ring);
}

// Round 8
// 341.392 us; speedup vs baseline: 2.9764x; 1.1230x over previous
//
#include <hip/hip_runtime.h>
#include <stdint.h>

#define WN 4096               // nodes
#define BN 32                 // batch
#define LN 96                 // gate layers
#define CN 16                 // owned nodes per block
#define HN 16                 // halo width (nodes)
#define NS (CN + HN)          // 32 node slots per block
#define GQ 8                  // batch groups of 4 (32/4)
#define TPB (NS * GQ)         // 256 threads, 4 waves
#define NBLK (WN / CN)        // 256 blocks (1 per CU)
#define NSS (LN / HN)         // 6 superstages of 16 gate layers

#define POISON64 0xAAAAAAAAAAAAAAAAULL

// ring layout identical to round 5 (proven): 5 exchanges x blk x node x batch x 4 u64
#define RING_SS_STRIDE ((size_t)NBLK * CN * BN * 4)
#define RING2_OFF ((size_t)(NSS - 1) * RING_SS_STRIDE)

static __device__ __forceinline__ float sigmoid_f(float z) {
    float e = __builtin_amdgcn_exp2f(z * -1.4426950408889634f);
    return __builtin_amdgcn_rcpf(1.0f + e);
}

static __device__ __forceinline__ uint64_t pack2(float a, float b) {
    union { float f[2]; uint64_t u; } u;
    u.f[0] = a; u.f[1] = b;
    return u.u;
}

static __device__ __forceinline__ void unpack2(uint64_t q, float& a, float& b) {
    union { uint64_t u; float f[2]; } u;
    u.u = q; a = u.f[0]; b = u.f[1];
}

// Sigmoid outputs in (0,1) are never bit-equal to 0xAA poison or 0 -> each u64
// is its own ready flag (verified: rounds 2/3/5 all absmax 0.0).
static __device__ __forceinline__ uint64_t poll64(const uint64_t* p) {
    uint64_t q;
    do {
        q = __hip_atomic_load(p, __ATOMIC_RELAXED, __HIP_MEMORY_SCOPE_AGENT);
    } while (q == POISON64 || q == 0ULL);
    return q;
}

__global__
__attribute__((amdgpu_flat_work_group_size(TPB, TPB), amdgpu_waves_per_eu(1, 1)))
void rh_halo_g4_kernel(
    const float* __restrict__ x,
    const float* __restrict__ w_top,
    const float* __restrict__ b_top,
    const float* __restrict__ w_gate,
    const float* __restrict__ b_gate,
    const float* __restrict__ w_prior,
    const float* __restrict__ b_prior,
    float* __restrict__ out,
    uint64_t* __restrict__ ring)
{
    const int tid  = threadIdx.x;
    const int j    = tid >> 3;               // node slot [0, NS); 8 consecutive lanes share a slot
    const int q    = tid & 7;                // batch group: batches 4q .. 4q+3
    const int blk  = blockIdx.x;
    const int node = (blk * CN - HN + j + WN) & (WN - 1);
    const bool isn0 = (node == 0);
    const int leftblk = (blk + NBLK - 1) & (NBLK - 1);

    // column c = m*8 + q holds odd-output (2m+1) for batches 4q..4q+3.
    // bank group = (j*32 + m*8 + q) % 8 = q -> distinct within each 8-lane chunk.
    __shared__ float4 lodds[2][NS][BN];      // 32 KB

    float y[8][4];                            // [output][batch-in-group]

    // ---------------- top layer: all slots ----------------
    {
        const float4* wt = (const float4*)(w_top + (size_t)node * 32);
        const float4* bt = (const float4*)(b_top + (size_t)node * 8);
        float4 c0 = bt[0], c1 = bt[1];
        float bb[8] = {c0.x, c0.y, c0.z, c0.w, c1.x, c1.y, c1.z, c1.w};
        float rs[8];
        #pragma unroll
        for (int o = 0; o < 8; ++o) { float4 a = wt[o]; rs[o] = a.x + a.y + a.z + a.w; }
        #pragma unroll
        for (int i = 0; i < 4; ++i) {
            float xv = x[(size_t)(q * 4 + i) * WN + node];
            #pragma unroll
            for (int o = 0; o < 8; ++o) y[o][i] = sigmoid_f(xv * rs[o] + bb[o]);
        }
    }

    const float4* wg_base = (const float4*)w_gate;
    const float4* bg_base = (const float4*)b_gate;

    // prefetched next-layer weights (72 floats live across the barrier;
    // VGPR budget pinned to 512 by waves_per_eu(1,1) -> no spill)
    float4 wa[16], wbl, wbh;
    if (j >= 1) {                             // layer 0's compute set is j >= 1
        const float4* wrow = wg_base + (size_t)node * 16;
        const float4* brow = bg_base + (size_t)node * 2;
        #pragma unroll
        for (int k = 0; k < 16; ++k) wa[k] = wrow[k];
        wbl = brow[0]; wbh = brow[1];
    }

    int par = 0;

    #pragma unroll 1
    for (int ss = 0; ss < NSS; ++ss) {
        #pragma unroll 1
        for (int t = 1; t <= HN; ++t) {
            // publish odds of current y (valid for j >= t-1)
            if (j >= t - 1) {
                #pragma unroll
                for (int m = 0; m < 4; ++m)
                    lodds[par][j][m * 8 + q] =
                        make_float4(y[2*m+1][0], y[2*m+1][1], y[2*m+1][2], y[2*m+1][3]);
            }

            __syncthreads();

            if (j >= t) {
                float h[8][4];
                #pragma unroll
                for (int m = 0; m < 4; ++m) {
                    float4 od = lodds[par][j - 1][m * 8 + q];
                    float odv[4] = {od.x, od.y, od.z, od.w};
                    #pragma unroll
                    for (int i = 0; i < 4; ++i) {
                        h[2*m][i]   = isn0 ? odv[i]    : y[2*m][i];
                        h[2*m+1][i] = isn0 ? y[2*m][i] : odv[i];
                    }
                }
                float bb[8] = {wbl.x, wbl.y, wbl.z, wbl.w, wbh.x, wbh.y, wbh.z, wbh.w};
                #pragma unroll
                for (int o = 0; o < 8; ++o) {
                    float4 a0 = wa[2*o], a1 = wa[2*o+1];
                    #pragma unroll
                    for (int i = 0; i < 4; ++i) {
                        float z = bb[o]
                            + a0.x*h[0][i] + a0.y*h[1][i] + a0.z*h[2][i] + a0.w*h[3][i]
                            + a1.x*h[4][i] + a1.y*h[5][i] + a1.z*h[6][i] + a1.w*h[7][i];
                        y[o][i] = sigmoid_f(z);
                    }
                }
            }

            // prefetch NEXT layer's weights (issued before next barrier/exchange;
            // in flight while other work proceeds)
            const int nlay = ss * HN + t;     // 0-based next layer index
            const int tn = (t == HN) ? 1 : t + 1;
            if (nlay < LN && j >= tn) {
                const float4* wrow = wg_base + ((size_t)nlay * WN + node) * 16;
                const float4* brow = bg_base + ((size_t)nlay * WN + node) * 2;
                #pragma unroll
                for (int k = 0; k < 16; ++k) wa[k] = wrow[k];
                wbl = brow[0]; wbh = brow[1];
            }

            par ^= 1;
        }

        // -------- superstage exchange: owned y -> right neighbor's halo ------
        if (ss < NSS - 1) {
            if (j >= HN) {
                const int own = j - HN;
                #pragma unroll
                for (int i = 0; i < 4; ++i) {
                    const int b = q * 4 + i;
                    uint64_t* slot = ring + (size_t)ss * RING_SS_STRIDE
                                   + (((size_t)blk * CN + own) * BN + b) * 4;
                    __hip_atomic_store(slot + 0, pack2(y[0][i], y[1][i]),
                                       __ATOMIC_RELAXED, __HIP_MEMORY_SCOPE_AGENT);
                    __hip_atomic_store(slot + 1, pack2(y[2][i], y[3][i]),
                                       __ATOMIC_RELAXED, __HIP_MEMORY_SCOPE_AGENT);
                    __hip_atomic_store(slot + 2, pack2(y[4][i], y[5][i]),
                                       __ATOMIC_RELAXED, __HIP_MEMORY_SCOPE_AGENT);
                    __hip_atomic_store(slot + 3, pack2(y[6][i], y[7][i]),
                                       __ATOMIC_RELAXED, __HIP_MEMORY_SCOPE_AGENT);
                }
            } else {
                #pragma unroll
                for (int i = 0; i < 4; ++i) {
                    const int b = q * 4 + i;
                    const uint64_t* src = ring + (size_t)ss * RING_SS_STRIDE
                                        + (((size_t)leftblk * CN + j) * BN + b) * 4;
                    unpack2(poll64(src + 0), y[0][i], y[1][i]);
                    unpack2(poll64(src + 1), y[2][i], y[3][i]);
                    unpack2(poll64(src + 2), y[4][i], y[5][i]);
                    unpack2(poll64(src + 3), y[6][i], y[7][i]);
                }
            }
        }
    }

    // ---------------- final routing + prior (owned slots only) ----------------
    if (j >= HN) {
        #pragma unroll
        for (int m = 0; m < 4; ++m)
            lodds[par][j][m * 8 + q] =
                make_float4(y[2*m+1][0], y[2*m+1][1], y[2*m+1][2], y[2*m+1][3]);
    }
    if (j == NS - 1) {
        #pragma unroll
        for (int i = 0; i < 4; ++i) {
            const int b = q * 4 + i;
            uint64_t* slot = ring + RING2_OFF + ((size_t)blk * BN + b) * 2;
            __hip_atomic_store(slot + 0, pack2(y[1][i], y[3][i]),
                               __ATOMIC_RELAXED, __HIP_MEMORY_SCOPE_AGENT);
            __hip_atomic_store(slot + 1, pack2(y[5][i], y[7][i]),
                               __ATOMIC_RELAXED, __HIP_MEMORY_SCOPE_AGENT);
        }
    }
    __syncthreads();

    if (j >= HN) {
        float od[4][4];                       // [m][i]
        if (j == HN) {
            #pragma unroll
            for (int i = 0; i < 4; ++i) {
                const int b = q * 4 + i;
                const uint64_t* src = ring + RING2_OFF + ((size_t)leftblk * BN + b) * 2;
                unpack2(poll64(src + 0), od[0][i], od[1][i]);
                unpack2(poll64(src + 1), od[2][i], od[3][i]);
            }
        } else {
            #pragma unroll
            for (int m = 0; m < 4; ++m) {
                float4 t4 = lodds[par][j - 1][m * 8 + q];
                od[m][0] = t4.x; od[m][1] = t4.y; od[m][2] = t4.z; od[m][3] = t4.w;
            }
        }
        const float4* wp = (const float4*)(w_prior + (size_t)node * 8);
        float4 p0 = wp[0], p1 = wp[1];
        float bp = b_prior[node];
        #pragma unroll
        for (int i = 0; i < 4; ++i) {
            float h[8];
            #pragma unroll
            for (int m = 0; m < 4; ++m) {
                h[2*m]   = isn0 ? od[m][i]  : y[2*m][i];
                h[2*m+1] = isn0 ? y[2*m][i] : od[m][i];
            }
            float logit = bp
                + p0.x*h[0] + p0.y*h[1] + p0.z*h[2] + p0.w*h[3]
                + p1.x*h[4] + p1.y*h[5] + p1.z*h[6] + p1.w*h[7];
            out[(size_t)(q * 4 + i) * WN + node] = logit;
        }
    }
}

extern "C" void kernel_launch(void* const* d_in, const int* in_sizes, int n_in,
                              void* d_out, int out_size, void* d_ws, size_t ws_size,
                              hipStream_t stream) {
    const float* x       = (const float*)d_in[0];
    const float* w_top   = (const float*)d_in[1];
    const float* b_top   = (const float*)d_in[2];
    const float* w_gate  = (const float*)d_in[3];
    const float* b_gate  = (const float*)d_in[4];
    const float* w_prior = (const float*)d_in[5];
    const float* b_prior = (const float*)d_in[6];
    float* out           = (float*)d_out;
    uint64_t* ring       = (uint64_t*)d_ws;  // 21.1 MB used

    hipLaunchKernelGGL(rh_halo_g4_kernel, dim3(NBLK), dim3(TPB), 0, stream,
                       x, w_top, b_top, w_gate, b_gate, w_prior, b_prior,
                       out, ring);
}

// Round 13
// 336.129 us; speedup vs baseline: 3.0230x; 1.0157x over previous
//
#include <hip/hip_runtime.h>
#include <stdint.h>

#define WN 4096
#define BN 32
#define LN 96
#define CN 16                  // nodes per block == waves per block
#define TPB (CN * 64)          // 1024 threads
#define NBLK (WN / CN)         // 256 blocks (1 per CU)
#define NST (LN + 1)           // 97 routing stages
#define NXCD 8

#define POISON64 0xAAAAAAAAAAAAAAAAULL

static __device__ __forceinline__ float sigmoid_f(float z) {
    float e = __builtin_amdgcn_exp2f(z * -1.4426950408889634f);
    return __builtin_amdgcn_rcpf(1.0f + e);
}
static __device__ __forceinline__ uint64_t pack2(float a, float b) {
    union { float f[2]; uint64_t u; } u; u.f[0] = a; u.f[1] = b; return u.u;
}
static __device__ __forceinline__ void unpack2(uint64_t q, float& a, float& b) {
    union { uint64_t u; float f[2]; } u; u.u = q; a = u.f[0]; b = u.f[1];
}
// Sigmoid outputs in (0,1) are never bit-equal to 0xAA poison or 0 -> each u64
// is its own ready flag (verified rounds 2/3/5/8, absmax ~0).
static __device__ __forceinline__ uint64_t poll64(const uint64_t* p) {
    uint64_t q;
    do { q = __hip_atomic_load(p, __ATOMIC_RELAXED, __HIP_MEMORY_SCOPE_AGENT); }
    while (q == POISON64 || q == 0ULL);
    return q;
}

__global__
__attribute__((amdgpu_flat_work_group_size(TPB, TPB), amdgpu_waves_per_eu(4, 4)))
void rh_wavenode_kernel(
    const float* __restrict__ x,
    const float* __restrict__ w_top,
    const float* __restrict__ b_top,
    const float* __restrict__ w_gate,
    const float* __restrict__ b_gate,
    const float* __restrict__ w_prior,
    const float* __restrict__ b_prior,
    float* __restrict__ out,
    uint64_t* __restrict__ ring)
{
    const int tid  = threadIdx.x;
    const int b    = tid & 31;            // batch lane
    const int half = (tid >> 5) & 1;      // output half: 0 -> o=0..3, 1 -> o=4..7
    // wave id (force wave-uniform so weight loads scalarize to s_load)
    const int jw   = __builtin_amdgcn_readfirstlane(tid >> 6);   // 0..CN-1
    // XCD-contiguous ring position: default dispatch round-robins blockIdx
    // across 8 XCDs; p = (bid%8)*32 + bid/8 puts ring-neighbors (p, p-1) on
    // the SAME XCD L2 for 248/256 boundaries -> cheap same-L2 hops.
    const int p    = ((int)blockIdx.x & (NXCD - 1)) * (NBLK / NXCD)
                   + ((int)blockIdx.x >> 3);
    const int node = p * CN + jw;
    const bool isn0 = (node == 0);
    const int leftp = (p + NBLK - 1) & (NBLK - 1);

    // odds pairs, parity double-buffered: [par][node-slot][half][batch]
    // bank: (2*(half*32+b)) % 32 -> b and b+16 share a pair: 2-way (free, m136)
    __shared__ uint64_t obuf[2][CN][2][BN];   // 16 KB

    float y0, y1, y2, y3;   // lane's outputs, globals half*4 + {0,1,2,3}

    // ---------------- top layer ----------------
    {
        const float* wt = w_top + (size_t)node * 32;   // uniform -> s_load
        const float* bt = b_top + (size_t)node * 8;    // uniform -> s_load
        float xv = x[(size_t)b * WN + node];
        float r0, r1, r2, r3, c0, c1, c2, c3;
        if (half == 0) {
            r0 = wt[0]+wt[1]+wt[2]+wt[3];     c0 = bt[0];
            r1 = wt[4]+wt[5]+wt[6]+wt[7];     c1 = bt[1];
            r2 = wt[8]+wt[9]+wt[10]+wt[11];   c2 = bt[2];
            r3 = wt[12]+wt[13]+wt[14]+wt[15]; c3 = bt[3];
        } else {
            r0 = wt[16]+wt[17]+wt[18]+wt[19]; c0 = bt[4];
            r1 = wt[20]+wt[21]+wt[22]+wt[23]; c1 = bt[5];
            r2 = wt[24]+wt[25]+wt[26]+wt[27]; c2 = bt[6];
            r3 = wt[28]+wt[29]+wt[30]+wt[31]; c3 = bt[7];
        }
        y0 = sigmoid_f(xv * r0 + c0);
        y1 = sigmoid_f(xv * r1 + c1);
        y2 = sigmoid_f(xv * r2 + c2);
        y3 = sigmoid_f(xv * r3 + c3);
    }

    #pragma unroll 1
    for (int s = 0; s < NST; ++s) {
        const int par = s & 1;

        // 1) publish odds: LDS for right-neighbor wave, ring for right block
        obuf[par][jw][half][b] = pack2(y1, y3);
        if (jw == CN - 1) {
            uint64_t* slot = ring + (((size_t)s * NBLK + p) * BN + b) * 2 + half;
            __hip_atomic_store(slot, pack2(y1, y3),
                               __ATOMIC_RELAXED, __HIP_MEMORY_SCOPE_AGENT);
        }

        // 2) cross-half evens exchange (intra-wave, no barrier needed)
        float oth0 = __shfl_xor(y0, 32, 64);
        float oth2 = __shfl_xor(y2, 32, 64);

        // 3) this stage's gate weights: wave-uniform address => s_load into
        //    SGPRs (no 64-lane VGPR replication). Issued before the barrier
        //    so SMEM latency hides under barrier + gather.
        float sw[64];
        float sb0 = 0.f, sb1 = 0.f, sb2 = 0.f, sb3 = 0.f;
        float sb4 = 0.f, sb5 = 0.f, sb6 = 0.f, sb7 = 0.f;
        if (s < LN) {
            const float* wrow = w_gate + ((size_t)s * WN + node) * 64;
            #pragma unroll
            for (int k = 0; k < 64; ++k) sw[k] = wrow[k];
            const float* brow = b_gate + ((size_t)s * WN + node) * 8;
            sb0 = brow[0]; sb1 = brow[1]; sb2 = brow[2]; sb3 = brow[3];
            sb4 = brow[4]; sb5 = brow[5]; sb6 = brow[6]; sb7 = brow[7];
        }

        __syncthreads();

        // 4) gather left-node odds (globals 1,3,5,7)
        float od1, od3, od5, od7;
        if (jw == 0) {
            const uint64_t* src = ring + (((size_t)s * NBLK + leftp) * BN + b) * 2;
            unpack2(poll64(src + 0), od1, od3);
            unpack2(poll64(src + 1), od5, od7);
        } else {
            unpack2(obuf[par][jw - 1][0][b], od1, od3);
            unpack2(obuf[par][jw - 1][1][b], od5, od7);
        }

        // 5) evens in global output order (half-dependent select)
        float g0 = half ? oth0 : y0;
        float g2 = half ? oth2 : y2;
        float g4 = half ? y0   : oth0;
        float g6 = half ? y2   : oth2;

        // 6) routing (node 0 swapped; wave-uniform branch)
        float h0, h1, h2, h3, h4, h5, h6, h7;
        if (isn0) {
            h0 = od1; h2 = od3; h4 = od5; h6 = od7;
            h1 = g0;  h3 = g2;  h5 = g4;  h7 = g6;
        } else {
            h0 = g0;  h2 = g2;  h4 = g4;  h6 = g6;
            h1 = od1; h3 = od3; h5 = od5; h7 = od7;
        }

        if (s == LN) {
            // ---------------- prior (no sigmoid) ----------------
            const float* wp = w_prior + (size_t)node * 8;   // uniform -> s_load
            float logit = b_prior[node]
                + wp[0]*h0 + wp[1]*h1 + wp[2]*h2 + wp[3]*h3
                + wp[4]*h4 + wp[5]*h5 + wp[6]*h6 + wp[7]*h7;
            if (half == 0) out[(size_t)b * WN + node] = logit;
            break;
        }

        // 7) gate layer s: divergent halves, each reads its own SGPR weights
        float z0, z1, z2, z3;
        if (half == 0) {
            z0 = sb0 + sw[ 0]*h0 + sw[ 1]*h1 + sw[ 2]*h2 + sw[ 3]*h3
                     + sw[ 4]*h4 + sw[ 5]*h5 + sw[ 6]*h6 + sw[ 7]*h7;
            z1 = sb1 + sw[ 8]*h0 + sw[ 9]*h1 + sw[10]*h2 + sw[11]*h3
                     + sw[12]*h4 + sw[13]*h5 + sw[14]*h6 + sw[15]*h7;
            z2 = sb2 + sw[16]*h0 + sw[17]*h1 + sw[18]*h2 + sw[19]*h3
                     + sw[20]*h4 + sw[21]*h5 + sw[22]*h6 + sw[23]*h7;
            z3 = sb3 + sw[24]*h0 + sw[25]*h1 + sw[26]*h2 + sw[27]*h3
                     + sw[28]*h4 + sw[29]*h5 + sw[30]*h6 + sw[31]*h7;
        } else {
            z0 = sb4 + sw[32]*h0 + sw[33]*h1 + sw[34]*h2 + sw[35]*h3
                     + sw[36]*h4 + sw[37]*h5 + sw[38]*h6 + sw[39]*h7;
            z1 = sb5 + sw[40]*h0 + sw[41]*h1 + sw[42]*h2 + sw[43]*h3
                     + sw[44]*h4 + sw[45]*h5 + sw[46]*h6 + sw[47]*h7;
            z2 = sb6 + sw[48]*h0 + sw[49]*h1 + sw[50]*h2 + sw[51]*h3
                     + sw[52]*h4 + sw[53]*h5 + sw[54]*h6 + sw[55]*h7;
            z3 = sb7 + sw[56]*h0 + sw[57]*h1 + sw[58]*h2 + sw[59]*h3
                     + sw[60]*h4 + sw[61]*h5 + sw[62]*h6 + sw[63]*h7;
        }
        y0 = sigmoid_f(z0);
        y1 = sigmoid_f(z1);
        y2 = sigmoid_f(z2);
        y3 = sigmoid_f(z3);
    }
}

extern "C" void kernel_launch(void* const* d_in, const int* in_sizes, int n_in,
                              void* d_out, int out_size, void* d_ws, size_t ws_size,
                              hipStream_t stream) {
    const float* x       = (const float*)d_in[0];
    const float* w_top   = (const float*)d_in[1];
    const float* b_top   = (const float*)d_in[2];
    const float* w_gate  = (const float*)d_in[3];
    const float* b_gate  = (const float*)d_in[4];
    const float* w_prior = (const float*)d_in[5];
    const float* b_prior = (const float*)d_in[6];
    float* out           = (float*)d_out;
    uint64_t* ring       = (uint64_t*)d_ws;   // 97*256*32*16 B = 12.7 MB (< 24.3 proven)

    hipLaunchKernelGGL(rh_wavenode_kernel, dim3(NBLK), dim3(TPB), 0, stream,
                       x, w_top, b_top, w_gate, b_gate, w_prior, b_prior,
                       out, ring);
}